// Round 9
// baseline (1730.317 us; speedup 1.0000x reference)
//
#include <hip/hip_runtime.h>

// OR_LSTM Round 17: ONE-HOP column broadcast with 8x-replicated partials.
// B=32,T=128,D=16,H=256,WS=8,OUT=8. 127 iterations, 8-slot window pipeline,
// 256 wgs = 8 slots x 32 col-groups, TPB=256.
// Model (R10-R16): cycle = 3 exposed sc0sc1 hops (colX, h0X, h1X/PB) x
// ~1.4us + compute + interference = 9.2us/iter. R15 proved the one-hop
// column idea but died on fan-in congestion (256 wgs polling ONE 32KB
// region). R17: finishing slot stores head partials (f32, 2-bit tag) to
// 8 SLOT-PRIVATE copies (512KB overlay on dead W1BH); each consumer polls
// only its own slot's copy (fan-in 32 wgs = the proven h0X pattern), sums,
// and maintains the feedback column in LDS (COL_ += blin + sum) --
// deterministic and identical in every wg. colX, BASE_, and the cw0
// funnel are DELETED (-2 serial hops, +1). sl7/cw0 writes out columns at
// consumption; column 119 via one-time epilogue poll. Rule kept: nothing
// reads the MALL inside the h0X store->poll window (B' is register-only).

#define NWG 256
#define TPB 256

typedef float f32x4 __attribute__((ext_vector_type(4)));
typedef _Float16 f16x8 __attribute__((ext_vector_type(8)));

// ---- workspace byte layout ----
#define CTRL_BYTES 4096
#define OFF_W0H   36864      // f16 [1024 cols][296]   (init-only source)
#define OFF_W1AH  643072     // f16 [1024][256]        (init-only source)
#define OFF_W1AL  1167360
#define OFF_W1BH  1691648
#define OFF_W1BL  2215936
// overlays (live after init grid barriers; zeroed in-kernel between them):
#define OFF_H0X   OFF_W1AH   // u32 [2 par][8 sl][32 r][256 u] {hi16,lo16+tag}
#define OFF_H1X   OFF_W1AL   // u32 [2 par][8 sl][32 r][256 u] {hi16,lo16+tag}
#define OFF_PBX   OFF_W1BH   // u32 [2 par][8 slcopy][256 tid][32 cw] f32|tag

// ---- ctrl u32 indices ----
#define IB1_U 32             // weights-read-done barrier
#define IB2_U 48             // zeroing-done barrier

// ---- dynamic LDS byte layout (<= 160KB) ----
#define L_W0H   0        // f16 [32][296]
#define L_W1AH  18944    // f16 [32][264]
#define L_W1AL  35840
#define L_W1BH  52736
#define L_W1BL  69632
#define L_ABH   86528    // f16 [32 rows][296]: x(0..15)|zero(16..31)|h0(32..287)
#define L_ABL   105472
#define L_H1H   124416   // f16 [32][264]
#define L_GATES 141312   // f32 [32][33]
#define L_WLIN  145536   // f32 [8][260]
#define L_HOWN  153856   // f32 [32][9]
#define L_COL   155008   // f32 [32][8]  maintained feedback column out[:,t]
#define L_B0    156032
#define L_B1    156160
#define L_BLIN  156288
#define SMEM_BYTES 156320

__device__ __forceinline__ float sigf(float x) { return 1.0f / (1.0f + __expf(-x)); }
__device__ __forceinline__ float tanhfast(float x) {
  float e = __expf(2.0f * x);
  return 1.0f - 2.0f / (e + 1.0f);
}
__device__ __forceinline__ unsigned f16u(_Float16 h) {
  union { _Float16 h; unsigned short u; } c; c.h = h; return c.u;
}
__device__ __forceinline__ unsigned fbits(float x) {
  union { float f; unsigned u; } c; c.f = x; return c.u;
}
__device__ __forceinline__ void splitpack(float x0, float x1, unsigned& hw, unsigned& lw) {
  const _Float16 a = (_Float16)x0, b = (_Float16)x1;
  hw = f16u(a) | (f16u(b) << 16);
  lw = f16u((_Float16)(x0 - (float)a)) | (f16u((_Float16)(x1 - (float)b)) << 16);
}

__device__ __forceinline__ unsigned rload(const unsigned* p) {
  return __hip_atomic_load(p, __ATOMIC_RELAXED, __HIP_MEMORY_SCOPE_AGENT);
}
// MALL (device-coherent) ops: sc0 sc1 -- the proven primitives.
__device__ __forceinline__ void mall_store_u32(unsigned* p, unsigned v) {
  asm volatile("global_store_dword %0, %1, off sc0 sc1" :: "v"(p), "v"(v) : "memory");
}
__device__ __forceinline__ void mall_load8x4(const void* p, f32x4& a0, f32x4& a1,
                                             f32x4& a2, f32x4& a3, f32x4& a4,
                                             f32x4& a5, f32x4& a6, f32x4& a7) {
  asm volatile(
      "global_load_dwordx4 %0, %8, off sc0 sc1\n\t"
      "global_load_dwordx4 %1, %8, off offset:16 sc0 sc1\n\t"
      "global_load_dwordx4 %2, %8, off offset:32 sc0 sc1\n\t"
      "global_load_dwordx4 %3, %8, off offset:48 sc0 sc1\n\t"
      "global_load_dwordx4 %4, %8, off offset:64 sc0 sc1\n\t"
      "global_load_dwordx4 %5, %8, off offset:80 sc0 sc1\n\t"
      "global_load_dwordx4 %6, %8, off offset:96 sc0 sc1\n\t"
      "global_load_dwordx4 %7, %8, off offset:112 sc0 sc1\n\t"
      "s_waitcnt vmcnt(0)"
      : "=&v"(a0), "=&v"(a1), "=&v"(a2), "=&v"(a3),
        "=&v"(a4), "=&v"(a5), "=&v"(a6), "=&v"(a7)
      : "v"(p) : "memory");
}
__device__ __forceinline__ void vmdrain() {
  asm volatile("s_waitcnt vmcnt(0)" ::: "memory");
}
__device__ __forceinline__ f32x4 mfma16(f16x8 a, f16x8 b, f32x4 c) {
  return __builtin_amdgcn_mfma_f32_16x16x32_f16(a, b, c, 0, 0, 0);
}

// tag checks: h0X/h1X words carry tag in bits 17:16; PBX f32 in bits 1:0.
#define TG4(vv, TAG) ((((fbits(vv.x) >> 16) & 3u) == (TAG)) & (((fbits(vv.y) >> 16) & 3u) == (TAG)) & \
                      (((fbits(vv.z) >> 16) & 3u) == (TAG)) & (((fbits(vv.w) >> 16) & 3u) == (TAG)))
#define TP4(vv, TAG) (((fbits(vv.x) & 3u) == (TAG)) & ((fbits(vv.y) & 3u) == (TAG)) & \
                      ((fbits(vv.z) & 3u) == (TAG)) & ((fbits(vv.w) & 3u) == (TAG)))
#define UNPK(vv, i2) {                                              \
    const unsigned w0 = fbits(vv.x), w1 = fbits(vv.y);              \
    const unsigned w2 = fbits(vv.z), w3 = fbits(vv.w);              \
    ah32[(i2)]     = (w0 & 0xffffu) | (w1 << 16);                   \
    ah32[(i2) + 1] = (w2 & 0xffffu) | (w3 << 16);                   \
    al32[(i2)]     = (w0 >> 16) | (w1 & 0xffff0000u);               \
    al32[(i2) + 1] = (w2 >> 16) | (w3 & 0xffff0000u); }
#define PKH(vv, i2) {                                               \
    dst[(i2)]     = (fbits(vv.x) & 0xffffu) | ((fbits(vv.y) & 0xffffu) << 16); \
    dst[(i2) + 1] = (fbits(vv.z) & 0xffffu) | ((fbits(vv.w) & 0xffffu) << 16); }
// spin-polls with s_sleep backoff
#define POLL8(srcp, TAG)                                             \
  { int fails = 0;                                                   \
    while (true) {                                                   \
      mall_load8x4(srcp, v0, v1, v2, v3, v4, v5, v6, v7);            \
      const unsigned ok = TG4(v0,TAG) & TG4(v1,TAG) & TG4(v2,TAG) &  \
                          TG4(v3,TAG) & TG4(v4,TAG) & TG4(v5,TAG) &  \
                          TG4(v6,TAG) & TG4(v7,TAG);                 \
      if (ok) break;                                                 \
      if (++fails > 1) __builtin_amdgcn_s_sleep(1);                  \
    } }
#define POLLPB(srcp, TAG)                                            \
  { int fails = 0;                                                   \
    while (true) {                                                   \
      mall_load8x4(srcp, v0, v1, v2, v3, v4, v5, v6, v7);            \
      const unsigned ok = TP4(v0,TAG) & TP4(v1,TAG) & TP4(v2,TAG) &  \
                          TP4(v3,TAG) & TP4(v4,TAG) & TP4(v5,TAG) &  \
                          TP4(v6,TAG) & TP4(v7,TAG);                 \
      if (ok) break;                                                 \
      if (++fails > 1) __builtin_amdgcn_s_sleep(1);                  \
    } }

// ---- prep (unchanged): pack weights into frag-ready f16 planes ----
__global__ __launch_bounds__(256) void lstm_prep(
    const float* __restrict__ Wih0, const float* __restrict__ Whh0,
    const float* __restrict__ Wih1, const float* __restrict__ Whh1,
    char* __restrict__ wsb) {
  const int i = blockIdx.x * 256 + threadIdx.x;
  _Float16* W0H = (_Float16*)(wsb + OFF_W0H);
  _Float16* W1AH = (_Float16*)(wsb + OFF_W1AH);
  _Float16* W1AL = (_Float16*)(wsb + OFF_W1AL);
  _Float16* W1BH = (_Float16*)(wsb + OFF_W1BH);
  _Float16* W1BL = (_Float16*)(wsb + OFF_W1BL);
  if (i < 1024 * 296) {           // W0 hi-only
    const int cg = i / 296, k = i - cg * 296;
    const int cw = cg >> 5, c = cg & 31;
    const int J = (c >> 3) * 256 + cw * 8 + (c & 7);
    float w = 0.f;
    if (k < 16) w = Wih0[J * 16 + k];
    else if (k >= 32 && k < 288) w = Whh0[J * 256 + (k - 32)];
    W0H[i] = (_Float16)w;
  }
  if (i < 1024 * 256) {           // W1A/W1B hi+lo
    const int cg = i >> 8, k = i & 255;
    const int cw = cg >> 5, c = cg & 31;
    const int J = (c >> 3) * 256 + cw * 8 + (c & 7);
    const float wa = Wih1[J * 256 + k];
    _Float16 h = (_Float16)wa;
    W1AH[i] = h; W1AL[i] = (_Float16)(wa - (float)h);
    const float wb = Whh1[J * 256 + k];
    h = (_Float16)wb;
    W1BH[i] = h; W1BL[i] = (_Float16)(wb - (float)h);
  }
}

__global__ __launch_bounds__(TPB, 1) void lstm_main(
    const float* __restrict__ traj,
    const float* __restrict__ bih0, const float* __restrict__ bhh0,
    const float* __restrict__ bih1, const float* __restrict__ bhh1,
    const float* __restrict__ Wlin, const float* __restrict__ blin,
    float* __restrict__ out, char* __restrict__ wsb) {
  extern __shared__ char smem[];
  _Float16* const W0H_  = (_Float16*)(smem + L_W0H);
  _Float16* const W1AH_ = (_Float16*)(smem + L_W1AH);
  _Float16* const W1AL_ = (_Float16*)(smem + L_W1AL);
  _Float16* const W1BH_ = (_Float16*)(smem + L_W1BH);
  _Float16* const W1BL_ = (_Float16*)(smem + L_W1BL);
  _Float16* const ABH_  = (_Float16*)(smem + L_ABH);
  _Float16* const ABL_  = (_Float16*)(smem + L_ABL);
  _Float16* const H1H_  = (_Float16*)(smem + L_H1H);
  float* const GATES_ = (float*)(smem + L_GATES);
  float* const WLIN_  = (float*)(smem + L_WLIN);
  float* const HOWN_  = (float*)(smem + L_HOWN);
  float* const COL_   = (float*)(smem + L_COL);
  float* const B0_    = (float*)(smem + L_B0);
  float* const B1_    = (float*)(smem + L_B1);
  float* const BLIN_  = (float*)(smem + L_BLIN);

  const int tid = threadIdx.x;
  const int wg = blockIdx.x;
  const int sl = wg & 7;           // pipeline slot
  const int cw = wg >> 3;          // col-group: units [cw*8, cw*8+8)
  unsigned* ctrl = (unsigned*)wsb;
  unsigned* const h0x = (unsigned*)(wsb + OFF_H0X);
  unsigned* const h1x = (unsigned*)(wsb + OFF_H1X);
  unsigned* const pbx = (unsigned*)(wsb + OFF_PBX);

  // ---- one-time LDS init from packed ws ----
  {
    const unsigned* s0 = (const unsigned*)(wsb + OFF_W0H) + cw * 4736;
    unsigned* d0 = (unsigned*)W0H_;
    for (int i = tid; i < 4736; i += TPB) d0[i] = s0[i];
    const unsigned* s1 = (const unsigned*)(wsb + OFF_W1AH) + cw * 4096;
    const unsigned* s2 = (const unsigned*)(wsb + OFF_W1AL) + cw * 4096;
    const unsigned* s3 = (const unsigned*)(wsb + OFF_W1BH) + cw * 4096;
    const unsigned* s4 = (const unsigned*)(wsb + OFF_W1BL) + cw * 4096;
    unsigned* d1 = (unsigned*)W1AH_; unsigned* d2 = (unsigned*)W1AL_;
    unsigned* d3 = (unsigned*)W1BH_; unsigned* d4 = (unsigned*)W1BL_;
    for (int i = tid; i < 4096; i += TPB) {
      const int c = i >> 7, d = i & 127;  // restride 128 -> 132 dwords
      d1[c * 132 + d] = s1[i];
      d2[c * 132 + d] = s2[i];
      d3[c * 132 + d] = s3[i];
      d4[c * 132 + d] = s4[i];
    }
    for (int i = tid; i < 2048; i += TPB)
      WLIN_[(i >> 8) * 260 + (i & 255)] = Wlin[i];
    if (tid < 32) {
      const int J = (tid >> 3) * 256 + cw * 8 + (tid & 7);
      B0_[tid] = bih0[J] + bhh0[J];
      B1_[tid] = bih1[J] + bhh1[J];
    }
    if (tid < 8) BLIN_[tid] = blin[tid];
    // COL init: base for out[:,0] = traj[:, 7, 8:16]
    COL_[tid] = traj[(tid >> 3) * 2048 + 7 * 16 + 8 + (tid & 7)];
    {  // permanent zero pad k=16..31 of AB
      const int r = tid >> 3, q = tid & 7;
      ((unsigned*)ABH_)[r * 148 + 8 + q] = 0u;
      ((unsigned*)ABL_)[r * 148 + 8 + q] = 0u;
    }
  }
  // grid barrier 1: everyone done READING overlay weight regions
  __syncthreads();
  if (tid == 0) {
    __hip_atomic_fetch_add(&ctrl[IB1_U], 1u, __ATOMIC_RELAXED,
                           __HIP_MEMORY_SCOPE_AGENT);
    while (rload(&ctrl[IB1_U]) < NWG) __builtin_amdgcn_s_sleep(1);
  }
  __syncthreads();
  // zero OWN exchange ranges: h0X/h1X (both parities) + pbx share (2KB/wg)
  {
    const int b = sl * 8192 + cw * 256 + tid;
    mall_store_u32(h0x + b, 0u);
    mall_store_u32(h0x + 65536 + b, 0u);
    mall_store_u32(h1x + b, 0u);
    mall_store_u32(h1x + 65536 + b, 0u);
    unsigned* z = pbx + wg * 512;
    mall_store_u32(z + tid, 0u);
    mall_store_u32(z + 256 + tid, 0u);
    vmdrain();
  }
  // grid barrier 2: zeroing visible before any exchange
  __syncthreads();
  if (tid == 0) {
    __hip_atomic_fetch_add(&ctrl[IB2_U], 1u, __ATOMIC_RELAXED,
                           __HIP_MEMORY_SCOPE_AGENT);
    while (rload(&ctrl[IB2_U]) < NWG) __builtin_amdgcn_s_sleep(1);
  }
  __syncthreads();

  // per-thread constants
  const int l = tid & 63, wv = tid >> 6;
  const int frow = ((wv >> 1) << 4) + (l & 15);
  const int fcol = ((wv & 1) << 4) + (l & 15);
  const int kg = (l >> 4) << 3;
  const int gr = ((wv >> 1) << 4) + ((l >> 4) << 2);
  const int rA = tid >> 3, uA = tid & 7;

  float c0s = 0.f, c1s = 0.f;

  for (int g = 0; g < 127; ++g) {
    const int s = (g - sl) & 7;
    const int t = g - s;
    if (t < 0 || t > 119) continue;
    const bool fresh = (s == 0);
    const int gb = g & 1;                                   // buffer parity
    const unsigned tagv = 1u | (((unsigned)(g >> 1) & 1u) << 1);

    // ---- A: L0 h0-part (16 MFMA; covers partials propagation) ----
    f32x4 acc0;
    { const float b = B0_[fcol]; acc0 = (f32x4){b, b, b, b}; }
    if (!fresh) {
      for (int ks = 0; ks < 8; ++ks) {
        const f16x8 ah = *(const f16x8*)(ABH_ + frow * 296 + 32 + ks * 32 + kg);
        const f16x8 al = *(const f16x8*)(ABL_ + frow * 296 + 32 + ks * 32 + kg);
        const f16x8 wh = *(const f16x8*)(W0H_ + fcol * 296 + 32 + ks * 32 + kg);
        acc0 = mfma16(ah, wh, acc0);
        acc0 = mfma16(al, wh, acc0);
      }
    }

    // ---- D0: poll OWN slot's partials copy -> COL_ update (g>=8) ----
    if (g >= 8) {
      const int tc = g - 8;
      const unsigned ptag = 1u | (((unsigned)(tc >> 1) & 1u) << 1);
      const unsigned* src = pbx + (tc & 1) * 65536 + sl * 8192 + tid * 32;
      f32x4 v0, v1, v2, v3, v4, v5, v6, v7;
      POLLPB(src, ptag)
      const float sum =
          v0.x + v0.y + v0.z + v0.w + v1.x + v1.y + v1.z + v1.w +
          v2.x + v2.y + v2.z + v2.w + v3.x + v3.y + v3.z + v3.w +
          v4.x + v4.y + v4.z + v4.w + v5.x + v5.y + v5.z + v5.w +
          v6.x + v6.y + v6.z + v6.w + v7.x + v7.y + v7.z + v7.w;
      const float nc = COL_[tid] + BLIN_[uA] + sum;
      COL_[tid] = nc;
      if (sl == 7 && cw == 0) out[rA * 960 + tc * 8 + uA] = nc;
    }
    __syncthreads();

    // ---- D: stage x -> AB[0..15] (feedback dims from LDS COL_) ----
    {
      const int r = tid >> 3, dp = (tid & 7) << 1;
      unsigned hw, lw;
      if (t <= 7 && s < 8 - t) {
        const float* tp = traj + r * 2048 + (t + s) * 16 + dp;
        splitpack(tp[0], tp[1], hw, lw);
      } else if (dp < 8) {
        const int ti = (t <= 7) ? (2 * t + s - 1) : (t + s);
        const float* tp = traj + r * 2048 + ti * 16 + dp;
        splitpack(tp[0], tp[1], hw, lw);
      } else {
        splitpack(COL_[r * 8 + dp - 8], COL_[r * 8 + dp - 7], hw, lw);
      }
      ((unsigned*)ABH_)[r * 148 + (dp >> 1)] = hw;
      ((unsigned*)ABL_)[r * 148 + (dp >> 1)] = lw;
    }
    __syncthreads();

    // ---- E: L0 x k-step, gates out ----
    {
      const f16x8 ah = *(const f16x8*)(ABH_ + frow * 296 + kg);
      const f16x8 al = *(const f16x8*)(ABL_ + frow * 296 + kg);
      const f16x8 wh = *(const f16x8*)(W0H_ + fcol * 296 + kg);
      acc0 = mfma16(ah, wh, acc0);
      acc0 = mfma16(al, wh, acc0);
#pragma unroll
      for (int q = 0; q < 4; ++q) GATES_[(gr + q) * 33 + fcol] = acc0[q];
    }
    __syncthreads();

    // ---- F: L0 act + h0X store (tag g) ----
    {
      const float iv = GATES_[rA * 33 + uA];
      const float fv = GATES_[rA * 33 + 8 + uA];
      const float gv = GATES_[rA * 33 + 16 + uA];
      const float ov = GATES_[rA * 33 + 24 + uA];
      const float cold = fresh ? 0.f : c0s;
      const float cn = sigf(fv) * cold + sigf(iv) * tanhfast(gv);
      c0s = cn;
      const float hv = sigf(ov) * tanhfast(cn);
      const _Float16 hh = (_Float16)hv;
      unsigned lo = f16u((_Float16)(hv - (float)hh));
      lo = (lo & 0xFFFCu) | tagv;
      mall_store_u32(h0x + gb * 65536 + sl * 8192 + rA * 256 + cw * 8 + uA,
                     f16u(hh) | (lo << 16));
      if (g == 126) {
        out[30720 + rA * 256 + cw * 8 + uA] = hv;   // h_n L0
        out[47104 + rA * 256 + cw * 8 + uA] = cn;   // c_n L0
      }
    }

    // ---- B': W1B*h1 (16 MFMA, register-only; fills h0X window) ----
    f32x4 acc1;
    { const float b = B1_[fcol]; acc1 = (f32x4){b, b, b, b}; }
    if (!fresh) {
      for (int ks = 0; ks < 8; ++ks) {
        const f16x8 hh = *(const f16x8*)(H1H_ + frow * 264 + ks * 32 + kg);
        const f16x8 wh = *(const f16x8*)(W1BH_ + fcol * 264 + ks * 32 + kg);
        const f16x8 wl = *(const f16x8*)(W1BL_ + fcol * 264 + ks * 32 + kg);
        acc1 = mfma16(hh, wh, acc1);
        acc1 = mfma16(hh, wl, acc1);
      }
    }

    // ---- H: poll-gather h0X (tag g) -> unpack into AB[32..287] ----
    {
      const int r = tid >> 3, c32 = (tid & 7) << 5;
      const unsigned* src = h0x + gb * 65536 + sl * 8192 + r * 256 + c32;
      f32x4 v0, v1, v2, v3, v4, v5, v6, v7;
      POLL8(src, tagv)
      unsigned* ah32 = (unsigned*)ABH_ + r * 148 + 16 + (c32 >> 1);
      unsigned* al32 = (unsigned*)ABL_ + r * 148 + 16 + (c32 >> 1);
      UNPK(v0, 0)  UNPK(v1, 2)  UNPK(v2, 4)  UNPK(v3, 6)
      UNPK(v4, 8)  UNPK(v5, 10) UNPK(v6, 12) UNPK(v7, 14)
    }
    __syncthreads();

    // ---- I: L1 W1A part (24 MFMA), gates out ----
    {
      for (int ks = 0; ks < 8; ++ks) {
        const f16x8 ah = *(const f16x8*)(ABH_ + frow * 296 + 32 + ks * 32 + kg);
        const f16x8 al = *(const f16x8*)(ABL_ + frow * 296 + 32 + ks * 32 + kg);
        const f16x8 wh = *(const f16x8*)(W1AH_ + fcol * 264 + ks * 32 + kg);
        const f16x8 wl = *(const f16x8*)(W1AL_ + fcol * 264 + ks * 32 + kg);
        acc1 = mfma16(ah, wh, acc1);
        acc1 = mfma16(al, wh, acc1);
        acc1 = mfma16(ah, wl, acc1);
      }
#pragma unroll
      for (int q = 0; q < 4; ++q) GATES_[(gr + q) * 33 + fcol] = acc1[q];
    }
    __syncthreads();

    // ---- J: L1 act; HOWN; h1X store (s<7 only) ----
    {
      const float iv = GATES_[rA * 33 + uA];
      const float fv = GATES_[rA * 33 + 8 + uA];
      const float gv = GATES_[rA * 33 + 16 + uA];
      const float ov = GATES_[rA * 33 + 24 + uA];
      const float cold = fresh ? 0.f : c1s;
      const float cn = sigf(fv) * cold + sigf(iv) * tanhfast(gv);
      c1s = cn;
      const float hv = sigf(ov) * tanhfast(cn);
      HOWN_[rA * 9 + uA] = hv;
      if (s < 7) {
        const _Float16 hh = (_Float16)hv;
        unsigned lo = f16u((_Float16)(hv - (float)hh));
        lo = (lo & 0xFFFCu) | tagv;
        mall_store_u32(h1x + gb * 65536 + sl * 8192 + rA * 256 + cw * 8 + uA,
                       f16u(hh) | (lo << 16));
      }
      if (g == 126) {
        out[38912 + rA * 256 + cw * 8 + uA] = hv;   // h_n L1
        out[55296 + rA * 256 + cw * 8 + uA] = cn;   // c_n L1
      }
    }
    __syncthreads();

    // ---- tail: s==7 -> partials to 8 slot-copies; s<7 -> h1X gather ----
    if (s == 7) {
      const unsigned ptag = 1u | (((unsigned)(t >> 1) & 1u) << 1);
      const float* wl = WLIN_ + uA * 260 + cw * 8;
      const float* hb = HOWN_ + rA * 9;
      float p = 0.f;
#pragma unroll
      for (int u = 0; u < 8; ++u) p = fmaf(hb[u], wl[u], p);
      const unsigned pu = (fbits(p) & ~3u) | ptag;
      unsigned* dst0 = pbx + (t & 1) * 65536 + tid * 32 + cw;
#pragma unroll
      for (int slc = 0; slc < 8; ++slc) mall_store_u32(dst0 + slc * 8192, pu);
      // epilogue: column 119 consumed by nobody -> sl7/cw0 polls + writes
      if (g == 126 && cw == 0) {
        const unsigned* src = pbx + (119 & 1) * 65536 + 7 * 8192 + tid * 32;
        f32x4 v0, v1, v2, v3, v4, v5, v6, v7;
        POLLPB(src, ptag)
        const float sum =
            v0.x + v0.y + v0.z + v0.w + v1.x + v1.y + v1.z + v1.w +
            v2.x + v2.y + v2.z + v2.w + v3.x + v3.y + v3.z + v3.w +
            v4.x + v4.y + v4.z + v4.w + v5.x + v5.y + v5.z + v5.w +
            v6.x + v6.y + v6.z + v6.w + v7.x + v7.y + v7.z + v7.w;
        out[rA * 960 + 119 * 8 + uA] = COL_[tid] + BLIN_[uA] + sum;
      }
    } else {
      const int r = tid >> 3, c32 = (tid & 7) << 5;
      const unsigned* src = h1x + gb * 65536 + sl * 8192 + r * 256 + c32;
      f32x4 v0, v1, v2, v3, v4, v5, v6, v7;
      POLL8(src, tagv)
      unsigned* dst = (unsigned*)H1H_ + r * 132 + (c32 >> 1);
      PKH(v0, 0)  PKH(v1, 2)  PKH(v2, 4)  PKH(v3, 6)
      PKH(v4, 8)  PKH(v5, 10) PKH(v6, 12) PKH(v7, 14)
    }
    __syncthreads();
  }
}

extern "C" void kernel_launch(void* const* d_in, const int* in_sizes, int n_in,
                              void* d_out, int out_size, void* d_ws, size_t ws_size,
                              hipStream_t stream) {
  (void)in_sizes; (void)n_in; (void)out_size; (void)ws_size;
  const float* traj = (const float*)d_in[0];
  const float* Wih0 = (const float*)d_in[1];
  const float* Whh0 = (const float*)d_in[2];
  const float* bih0 = (const float*)d_in[3];
  const float* bhh0 = (const float*)d_in[4];
  const float* Wih1 = (const float*)d_in[5];
  const float* Whh1 = (const float*)d_in[6];
  const float* bih1 = (const float*)d_in[7];
  const float* bhh1 = (const float*)d_in[8];
  const float* Wlin = (const float*)d_in[9];
  const float* blin = (const float*)d_in[10];
  float* out = (float*)d_out;
  char* wsb = (char*)d_ws;

  static bool attr_done = false;
  if (!attr_done) {
    (void)hipFuncSetAttribute((const void*)lstm_main,
                              hipFuncAttributeMaxDynamicSharedMemorySize,
                              SMEM_BYTES);
    attr_done = true;
  }

  hipMemsetAsync(d_ws, 0, CTRL_BYTES, stream);
  lstm_prep<<<1184, 256, 0, stream>>>(Wih0, Whh0, Wih1, Whh1, wsb);

  void* args[] = {(void*)&traj, (void*)&bih0, (void*)&bhh0, (void*)&bih1,
                  (void*)&bhh1, (void*)&Wlin, (void*)&blin, (void*)&out,
                  (void*)&wsb};
  hipLaunchCooperativeKernel((void*)lstm_main, dim3(NWG), dim3(TPB), args,
                             SMEM_BYTES, stream);
}

// Round 10
// 1196.088 us; speedup vs baseline: 1.4466x; 1.4466x over previous
//
#include <hip/hip_runtime.h>

// OR_LSTM Round 18: R11 EXACT skeleton + two protocol-preserving trims.
// B=32,T=128,D=16,H=256,WS=8,OUT=8. 127 iterations, 8-slot window pipeline,
// 256 wgs = 8 slots x 32 col-groups, TPB=256.
// Verdict from R14-R17 (all regressed): R11's 3-hop tag-in-data protocol is
// the structural floor (~1.4us per MALL store->poll hop, incl. own-store
// visibility; hop-removal attempts die on (a) reads inside store->poll
// windows or (b) MALL fan-out amplification). R18 keeps the protocol
// byte-identical and trims only:
//  1) h1X half-payload: consumer discards lo16 anyway (W1B is hi-only) ->
//     ship 2 units' hi-f16 per u32 (pack via __shfl_xor(1)); tag = bit0 of
//     each u16 (write-flag | generation). Halves h1X burst + poll payload.
//  2) post-J barrier only for s==7 (HOWN_ hazard); s<7 tail gather is
//     protocol-ordered, no LDS hazard (H/I barriers cover H1H_ WAR).

#define NWG 256
#define TPB 256

typedef float f32x4 __attribute__((ext_vector_type(4)));
typedef _Float16 f16x8 __attribute__((ext_vector_type(8)));
typedef unsigned u32x2 __attribute__((ext_vector_type(2)));

// ---- workspace byte layout ----
#define CTRL_BYTES 4096
#define OFF_W0H   36864      // f16 [1024 cols][296]   (init-only source)
#define OFF_W1AH  643072     // f16 [1024][256]        (init-only source)
#define OFF_W1AL  1167360
#define OFF_W1BH  1691648
#define OFF_W1BL  2215936
// overlays (live after init grid barriers; zeroed in-kernel between them):
#define OFF_H0X   OFF_W1AH   // u32 [2 par][8 sl][32 r][256 u] {hi16,lo16+tag}
#define OFF_H1X   OFF_W1AL   // u32 [2 par][8 sl][32 r][128 pair] {2x hi16|tagbit}
// never-written-by-prep region (zeroed by memsetAsync):
#define OFF_COLX  2740224    // u32 [120 t][32 r][8 o]  {hi16, lo16|bit0}
#define OFF_PB    2863104    // f32 [2 par][256 (r*8+o)][32 cw]  bits1:0=tag
#define PBCOLX_BYTES 188416  // 122880 + 65536

// ---- ctrl u32 indices ----
#define IB1_U 32             // weights-read-done barrier
#define IB2_U 48             // zeroing-done barrier

// ---- dynamic LDS byte layout (<= 160KB) ----
#define L_W0H   0        // f16 [32][296]
#define L_W1AH  18944    // f16 [32][264]
#define L_W1AL  35840
#define L_W1BH  52736
#define L_W1BL  69632
#define L_ABH   86528    // f16 [32 rows][296]: x(0..15)|zero(16..31)|h0(32..287)
#define L_ABL   105472
#define L_H1H   124416   // f16 [32][264]
#define L_GATES 141312   // f32 [32][33]
#define L_WLIN  145536   // f32 [8][260]
#define L_HOWN  153856   // f32 [32][9]
#define L_BASE  155008   // f32 [32][8]
#define L_B0    156032
#define L_B1    156160
#define L_BLIN  156288
#define SMEM_BYTES 156320

__device__ __forceinline__ float sigf(float x) { return 1.0f / (1.0f + __expf(-x)); }
__device__ __forceinline__ float tanhfast(float x) {
  float e = __expf(2.0f * x);
  return 1.0f - 2.0f / (e + 1.0f);
}
__device__ __forceinline__ unsigned f16u(_Float16 h) {
  union { _Float16 h; unsigned short u; } c; c.h = h; return c.u;
}
__device__ __forceinline__ float uf16(unsigned u) {
  union { unsigned short s; _Float16 h; } c; c.s = (unsigned short)u; return (float)c.h;
}
__device__ __forceinline__ unsigned fbits(float x) {
  union { float f; unsigned u; } c; c.f = x; return c.u;
}
__device__ __forceinline__ void splitpack(float x0, float x1, unsigned& hw, unsigned& lw) {
  const _Float16 a = (_Float16)x0, b = (_Float16)x1;
  hw = f16u(a) | (f16u(b) << 16);
  lw = f16u((_Float16)(x0 - (float)a)) | (f16u((_Float16)(x1 - (float)b)) << 16);
}

__device__ __forceinline__ unsigned rload(const unsigned* p) {
  return __hip_atomic_load(p, __ATOMIC_RELAXED, __HIP_MEMORY_SCOPE_AGENT);
}
// MALL (device-coherent) ops: sc0 sc1 -- the proven primitives.
__device__ __forceinline__ void mall_store_u32(unsigned* p, unsigned v) {
  asm volatile("global_store_dword %0, %1, off sc0 sc1" :: "v"(p), "v"(v) : "memory");
}
__device__ __forceinline__ void mall_load2(const void* p, unsigned& x, unsigned& y) {
  u32x2 v;
  asm volatile("global_load_dwordx2 %0, %1, off sc0 sc1\n\ts_waitcnt vmcnt(0)"
               : "=v"(v) : "v"(p) : "memory");
  x = v.x; y = v.y;
}
__device__ __forceinline__ void mall_load4x4(const void* p, f32x4& a, f32x4& b,
                                             f32x4& c, f32x4& d) {
  asm volatile(
      "global_load_dwordx4 %0, %4, off sc0 sc1\n\t"
      "global_load_dwordx4 %1, %4, off offset:16 sc0 sc1\n\t"
      "global_load_dwordx4 %2, %4, off offset:32 sc0 sc1\n\t"
      "global_load_dwordx4 %3, %4, off offset:48 sc0 sc1\n\t"
      "s_waitcnt vmcnt(0)"
      : "=&v"(a), "=&v"(b), "=&v"(c), "=&v"(d) : "v"(p) : "memory");
}
__device__ __forceinline__ void mall_load8x4(const void* p, f32x4& a0, f32x4& a1,
                                             f32x4& a2, f32x4& a3, f32x4& a4,
                                             f32x4& a5, f32x4& a6, f32x4& a7) {
  asm volatile(
      "global_load_dwordx4 %0, %8, off sc0 sc1\n\t"
      "global_load_dwordx4 %1, %8, off offset:16 sc0 sc1\n\t"
      "global_load_dwordx4 %2, %8, off offset:32 sc0 sc1\n\t"
      "global_load_dwordx4 %3, %8, off offset:48 sc0 sc1\n\t"
      "global_load_dwordx4 %4, %8, off offset:64 sc0 sc1\n\t"
      "global_load_dwordx4 %5, %8, off offset:80 sc0 sc1\n\t"
      "global_load_dwordx4 %6, %8, off offset:96 sc0 sc1\n\t"
      "global_load_dwordx4 %7, %8, off offset:112 sc0 sc1\n\t"
      "s_waitcnt vmcnt(0)"
      : "=&v"(a0), "=&v"(a1), "=&v"(a2), "=&v"(a3),
        "=&v"(a4), "=&v"(a5), "=&v"(a6), "=&v"(a7)
      : "v"(p) : "memory");
}
__device__ __forceinline__ void vmdrain() {
  asm volatile("s_waitcnt vmcnt(0)" ::: "memory");
}
__device__ __forceinline__ f32x4 mfma16(f16x8 a, f16x8 b, f32x4 c) {
  return __builtin_amdgcn_mfma_f32_16x16x32_f16(a, b, c, 0, 0, 0);
}

// tag checks: h0X words carry tag in bits 17:16; PB f32 in bits 1:0;
// h1X packed words carry {bit0 = written, bit16 = generation}.
#define TG4(vv, TAG) ((((fbits(vv.x) >> 16) & 3u) == (TAG)) & (((fbits(vv.y) >> 16) & 3u) == (TAG)) & \
                      (((fbits(vv.z) >> 16) & 3u) == (TAG)) & (((fbits(vv.w) >> 16) & 3u) == (TAG)))
#define TP4(vv, TAG) (((fbits(vv.x) & 3u) == (TAG)) & ((fbits(vv.y) & 3u) == (TAG)) & \
                      ((fbits(vv.z) & 3u) == (TAG)) & ((fbits(vv.w) & 3u) == (TAG)))
#define TH4(vv, TPAT) (((fbits(vv.x) & 0x10001u) == (TPAT)) & ((fbits(vv.y) & 0x10001u) == (TPAT)) & \
                       ((fbits(vv.z) & 0x10001u) == (TPAT)) & ((fbits(vv.w) & 0x10001u) == (TPAT)))
#define UNPK(vv, i2) {                                              \
    const unsigned w0 = fbits(vv.x), w1 = fbits(vv.y);              \
    const unsigned w2 = fbits(vv.z), w3 = fbits(vv.w);              \
    ah32[(i2)]     = (w0 & 0xffffu) | (w1 << 16);                   \
    ah32[(i2) + 1] = (w2 & 0xffffu) | (w3 << 16);                   \
    al32[(i2)]     = (w0 >> 16) | (w1 & 0xffff0000u);               \
    al32[(i2) + 1] = (w2 >> 16) | (w3 & 0xffff0000u); }
#define WRM(vv, i) {                                                \
    dst[(i)]     = fbits(vv.x) & 0xFFFEFFFEu;                       \
    dst[(i) + 1] = fbits(vv.y) & 0xFFFEFFFEu;                       \
    dst[(i) + 2] = fbits(vv.z) & 0xFFFEFFFEu;                       \
    dst[(i) + 3] = fbits(vv.w) & 0xFFFEFFFEu; }
#define POLL8(srcp, TAG)                                             \
  { while (true) {                                                   \
      mall_load8x4(srcp, v0, v1, v2, v3, v4, v5, v6, v7);            \
      const unsigned ok = TG4(v0,TAG) & TG4(v1,TAG) & TG4(v2,TAG) &  \
                          TG4(v3,TAG) & TG4(v4,TAG) & TG4(v5,TAG) &  \
                          TG4(v6,TAG) & TG4(v7,TAG);                 \
      if (ok) break;                                                 \
    } }
#define POLLPB(srcp, TAG)                                            \
  { while (true) {                                                   \
      mall_load8x4(srcp, v0, v1, v2, v3, v4, v5, v6, v7);            \
      const unsigned ok = TP4(v0,TAG) & TP4(v1,TAG) & TP4(v2,TAG) &  \
                          TP4(v3,TAG) & TP4(v4,TAG) & TP4(v5,TAG) &  \
                          TP4(v6,TAG) & TP4(v7,TAG);                 \
      if (ok) break;                                                 \
    } }
#define POLL4H(srcp, TPAT)                                           \
  { while (true) {                                                   \
      mall_load4x4(srcp, v0, v1, v2, v3);                            \
      const unsigned ok = TH4(v0,TPAT) & TH4(v1,TPAT) &              \
                          TH4(v2,TPAT) & TH4(v3,TPAT);               \
      if (ok) break;                                                 \
    } }

// ---- prep (unchanged): pack weights into frag-ready f16 planes ----
__global__ __launch_bounds__(256) void lstm_prep(
    const float* __restrict__ Wih0, const float* __restrict__ Whh0,
    const float* __restrict__ Wih1, const float* __restrict__ Whh1,
    char* __restrict__ wsb) {
  const int i = blockIdx.x * 256 + threadIdx.x;
  _Float16* W0H = (_Float16*)(wsb + OFF_W0H);
  _Float16* W1AH = (_Float16*)(wsb + OFF_W1AH);
  _Float16* W1AL = (_Float16*)(wsb + OFF_W1AL);
  _Float16* W1BH = (_Float16*)(wsb + OFF_W1BH);
  _Float16* W1BL = (_Float16*)(wsb + OFF_W1BL);
  if (i < 1024 * 296) {           // W0 hi-only
    const int cg = i / 296, k = i - cg * 296;
    const int cw = cg >> 5, c = cg & 31;
    const int J = (c >> 3) * 256 + cw * 8 + (c & 7);
    float w = 0.f;
    if (k < 16) w = Wih0[J * 16 + k];
    else if (k >= 32 && k < 288) w = Whh0[J * 256 + (k - 32)];
    W0H[i] = (_Float16)w;
  }
  if (i < 1024 * 256) {           // W1A/W1B hi+lo
    const int cg = i >> 8, k = i & 255;
    const int cw = cg >> 5, c = cg & 31;
    const int J = (c >> 3) * 256 + cw * 8 + (c & 7);
    const float wa = Wih1[J * 256 + k];
    _Float16 h = (_Float16)wa;
    W1AH[i] = h; W1AL[i] = (_Float16)(wa - (float)h);
    const float wb = Whh1[J * 256 + k];
    h = (_Float16)wb;
    W1BH[i] = h; W1BL[i] = (_Float16)(wb - (float)h);
  }
}

__global__ __launch_bounds__(TPB, 1) void lstm_main(
    const float* __restrict__ traj,
    const float* __restrict__ bih0, const float* __restrict__ bhh0,
    const float* __restrict__ bih1, const float* __restrict__ bhh1,
    const float* __restrict__ Wlin, const float* __restrict__ blin,
    float* __restrict__ out, char* __restrict__ wsb) {
  extern __shared__ char smem[];
  _Float16* const W0H_  = (_Float16*)(smem + L_W0H);
  _Float16* const W1AH_ = (_Float16*)(smem + L_W1AH);
  _Float16* const W1AL_ = (_Float16*)(smem + L_W1AL);
  _Float16* const W1BH_ = (_Float16*)(smem + L_W1BH);
  _Float16* const W1BL_ = (_Float16*)(smem + L_W1BL);
  _Float16* const ABH_  = (_Float16*)(smem + L_ABH);
  _Float16* const ABL_  = (_Float16*)(smem + L_ABL);
  _Float16* const H1H_  = (_Float16*)(smem + L_H1H);
  float* const GATES_ = (float*)(smem + L_GATES);
  float* const WLIN_  = (float*)(smem + L_WLIN);
  float* const HOWN_  = (float*)(smem + L_HOWN);
  float* const BASE_  = (float*)(smem + L_BASE);
  float* const B0_    = (float*)(smem + L_B0);
  float* const B1_    = (float*)(smem + L_B1);
  float* const BLIN_  = (float*)(smem + L_BLIN);

  const int tid = threadIdx.x;
  const int wg = blockIdx.x;
  const int sl = wg & 7;           // pipeline slot
  const int cw = wg >> 3;          // col-group: units [cw*8, cw*8+8)
  unsigned* ctrl = (unsigned*)wsb;
  unsigned* const h0x = (unsigned*)(wsb + OFF_H0X);
  unsigned* const h1x = (unsigned*)(wsb + OFF_H1X);
  unsigned* const colx = (unsigned*)(wsb + OFF_COLX);
  float* const pb = (float*)(wsb + OFF_PB);

  // ---- one-time LDS init from packed ws ----
  {
    const unsigned* s0 = (const unsigned*)(wsb + OFF_W0H) + cw * 4736;
    unsigned* d0 = (unsigned*)W0H_;
    for (int i = tid; i < 4736; i += TPB) d0[i] = s0[i];
    const unsigned* s1 = (const unsigned*)(wsb + OFF_W1AH) + cw * 4096;
    const unsigned* s2 = (const unsigned*)(wsb + OFF_W1AL) + cw * 4096;
    const unsigned* s3 = (const unsigned*)(wsb + OFF_W1BH) + cw * 4096;
    const unsigned* s4 = (const unsigned*)(wsb + OFF_W1BL) + cw * 4096;
    unsigned* d1 = (unsigned*)W1AH_; unsigned* d2 = (unsigned*)W1AL_;
    unsigned* d3 = (unsigned*)W1BH_; unsigned* d4 = (unsigned*)W1BL_;
    for (int i = tid; i < 4096; i += TPB) {
      const int c = i >> 7, d = i & 127;  // restride 128 -> 132 dwords
      d1[c * 132 + d] = s1[i];
      d2[c * 132 + d] = s2[i];
      d3[c * 132 + d] = s3[i];
      d4[c * 132 + d] = s4[i];
    }
    for (int i = tid; i < 2048; i += TPB)
      WLIN_[(i >> 8) * 260 + (i & 255)] = Wlin[i];
    if (tid < 32) {
      const int J = (tid >> 3) * 256 + cw * 8 + (tid & 7);
      B0_[tid] = bih0[J] + bhh0[J];
      B1_[tid] = bih1[J] + bhh1[J];
    }
    if (tid < 8) BLIN_[tid] = blin[tid];
    {  // permanent zero pad k=16..31 of AB
      const int r = tid >> 3, q = tid & 7;
      ((unsigned*)ABH_)[r * 148 + 8 + q] = 0u;
      ((unsigned*)ABL_)[r * 148 + 8 + q] = 0u;
    }
  }
  // grid barrier 1: everyone done READING overlay weight regions
  __syncthreads();
  if (tid == 0) {
    __hip_atomic_fetch_add(&ctrl[IB1_U], 1u, __ATOMIC_RELAXED,
                           __HIP_MEMORY_SCOPE_AGENT);
    while (rload(&ctrl[IB1_U]) < NWG) __builtin_amdgcn_s_sleep(1);
  }
  __syncthreads();
  // zero OWN (sl,cw) exchange ranges (both parities)
  {
    const int b = sl * 8192 + cw * 256 + tid;
    mall_store_u32(h0x + b, 0u);
    mall_store_u32(h0x + 65536 + b, 0u);
    if (tid < 128) {   // h1X packed: 128 words per parity per wg
      const int w = sl * 4096 + (tid >> 2) * 128 + cw * 4 + (tid & 3);
      mall_store_u32(h1x + w, 0u);
      mall_store_u32(h1x + 32768 + w, 0u);
    }
    vmdrain();
  }
  // grid barrier 2: zeroing visible before any exchange
  __syncthreads();
  if (tid == 0) {
    __hip_atomic_fetch_add(&ctrl[IB2_U], 1u, __ATOMIC_RELAXED,
                           __HIP_MEMORY_SCOPE_AGENT);
    while (rload(&ctrl[IB2_U]) < NWG) __builtin_amdgcn_s_sleep(1);
  }
  __syncthreads();

  // per-thread constants
  const int l = tid & 63, wv = tid >> 6;
  const int frow = ((wv >> 1) << 4) + (l & 15);
  const int fcol = ((wv & 1) << 4) + (l & 15);
  const int kg = (l >> 4) << 3;
  const int gr = ((wv >> 1) << 4) + ((l >> 4) << 2);
  const int rA = tid >> 3, uA = tid & 7;

  float c0s = 0.f, c1s = 0.f;

  for (int g = 0; g < 127; ++g) {
    const int s = (g - sl) & 7;
    const int t = g - s;
    if (t < 0 || t > 119) continue;
    const bool fresh = (s == 0);
    const int gb = g & 1;                            // buffer parity
    const unsigned tagv = 1u | (((unsigned)(g >> 1) & 1u) << 1);  // {bit1,bit0}
    const unsigned tpat = 1u | (((tagv >> 1) & 1u) << 16);        // h1X pattern

    // ---- A: L0 h0-part (pre-feedback; AB h0 gathered last iteration) ----
    f32x4 acc0;
    { const float b = B0_[fcol]; acc0 = (f32x4){b, b, b, b}; }
    if (!fresh) {
      for (int ks = 0; ks < 8; ++ks) {
        const f16x8 ah = *(const f16x8*)(ABH_ + frow * 296 + 32 + ks * 32 + kg);
        const f16x8 al = *(const f16x8*)(ABL_ + frow * 296 + 32 + ks * 32 + kg);
        const f16x8 wh = *(const f16x8*)(W0H_ + fcol * 296 + 32 + ks * 32 + kg);
        acc0 = mfma16(ah, wh, acc0);
        acc0 = mfma16(al, wh, acc0);
      }
    }

    // ---- D: stage x -> AB[0..15]; feedback dims poll tagged colX ----
    {
      const int r = tid >> 3, dp = (tid & 7) << 1;
      unsigned hw, lw;
      if (t <= 7 && s < 8 - t) {
        const float* tp = traj + r * 2048 + (t + s) * 16 + dp;
        splitpack(tp[0], tp[1], hw, lw);
      } else if (dp < 8) {
        const int ti = (t <= 7) ? (2 * t + s - 1) : (t + s);
        const float* tp = traj + r * 2048 + ti * 16 + dp;
        splitpack(tp[0], tp[1], hw, lw);
      } else {
        const unsigned* cp = colx + (g - 8) * 256 + r * 8 + (dp - 8);
        unsigned w0, w1;
        do { mall_load2(cp, w0, w1); } while (!(w0 & 0x10000u) || !(w1 & 0x10000u));
        hw = (w0 & 0xffffu) | ((w1 & 0xffffu) << 16);
        lw = (w0 >> 16) | (w1 & 0xffff0000u);
        if (s == 7) {  // cache finisher base out[:,t-1]
          BASE_[r * 8 + dp - 8] = uf16(w0 & 0xffffu) + uf16(w0 >> 16);
          BASE_[r * 8 + dp - 7] = uf16(w1 & 0xffffu) + uf16(w1 >> 16);
        }
      }
      ((unsigned*)ABH_)[r * 148 + (dp >> 1)] = hw;
      ((unsigned*)ABL_)[r * 148 + (dp >> 1)] = lw;
    }
    __syncthreads();

    // ---- E: L0 x k-step, gates out ----
    {
      const f16x8 ah = *(const f16x8*)(ABH_ + frow * 296 + kg);
      const f16x8 al = *(const f16x8*)(ABL_ + frow * 296 + kg);
      const f16x8 wh = *(const f16x8*)(W0H_ + fcol * 296 + kg);
      acc0 = mfma16(ah, wh, acc0);
      acc0 = mfma16(al, wh, acc0);
#pragma unroll
      for (int q = 0; q < 4; ++q) GATES_[(gr + q) * 33 + fcol] = acc0[q];
    }
    __syncthreads();

    // ---- F: L0 act + tagged h0X publish ----
    {
      const float iv = GATES_[rA * 33 + uA];
      const float fv = GATES_[rA * 33 + 8 + uA];
      const float gv = GATES_[rA * 33 + 16 + uA];
      const float ov = GATES_[rA * 33 + 24 + uA];
      const float cold = fresh ? 0.f : c0s;
      const float cn = sigf(fv) * cold + sigf(iv) * tanhfast(gv);
      c0s = cn;
      const float hv = sigf(ov) * tanhfast(cn);
      const _Float16 hh = (_Float16)hv;
      unsigned lo = f16u((_Float16)(hv - (float)hh));
      lo = (lo & 0xFFFCu) | tagv;
      mall_store_u32(h0x + gb * 65536 + sl * 8192 + rA * 256 + cw * 8 + uA,
                     f16u(hh) | (lo << 16));
      if (g == 126) {
        out[30720 + rA * 256 + cw * 8 + uA] = hv;   // h_n L0
        out[47104 + rA * 256 + cw * 8 + uA] = cn;   // c_n L0
      }
    }

    // ---- B': W1B*h1 (register-only; fills the h0X store->poll window) ----
    f32x4 acc1;
    { const float b = B1_[fcol]; acc1 = (f32x4){b, b, b, b}; }
    if (!fresh) {
      for (int ks = 0; ks < 8; ++ks) {
        const f16x8 hh = *(const f16x8*)(H1H_ + frow * 264 + ks * 32 + kg);
        const f16x8 wh = *(const f16x8*)(W1BH_ + fcol * 264 + ks * 32 + kg);
        const f16x8 wl = *(const f16x8*)(W1BL_ + fcol * 264 + ks * 32 + kg);
        acc1 = mfma16(hh, wh, acc1);
        acc1 = mfma16(hh, wl, acc1);
      }
    }

    // ---- H: poll-gather tagged h0X -> unpack into AB[32..287] ----
    {
      const int r = tid >> 3, c32 = (tid & 7) << 5;
      const unsigned* src = h0x + gb * 65536 + sl * 8192 + r * 256 + c32;
      f32x4 v0, v1, v2, v3, v4, v5, v6, v7;
      POLL8(src, tagv)
      unsigned* ah32 = (unsigned*)ABH_ + r * 148 + 16 + (c32 >> 1);
      unsigned* al32 = (unsigned*)ABL_ + r * 148 + 16 + (c32 >> 1);
      UNPK(v0, 0)  UNPK(v1, 2)  UNPK(v2, 4)  UNPK(v3, 6)
      UNPK(v4, 8)  UNPK(v5, 10) UNPK(v6, 12) UNPK(v7, 14)
    }
    __syncthreads();

    // ---- I: L1 W1A part (3 products), gates out ----
    {
      for (int ks = 0; ks < 8; ++ks) {
        const f16x8 ah = *(const f16x8*)(ABH_ + frow * 296 + 32 + ks * 32 + kg);
        const f16x8 al = *(const f16x8*)(ABL_ + frow * 296 + 32 + ks * 32 + kg);
        const f16x8 wh = *(const f16x8*)(W1AH_ + fcol * 264 + ks * 32 + kg);
        const f16x8 wl = *(const f16x8*)(W1AL_ + fcol * 264 + ks * 32 + kg);
        acc1 = mfma16(ah, wh, acc1);
        acc1 = mfma16(al, wh, acc1);
        acc1 = mfma16(ah, wl, acc1);
      }
#pragma unroll
      for (int q = 0; q < 4; ++q) GATES_[(gr + q) * 33 + fcol] = acc1[q];
    }
    __syncthreads();

    // ---- J: L1 act; HOWN; packed hi-only h1X publish (s<7) ----
    {
      const float iv = GATES_[rA * 33 + uA];
      const float fv = GATES_[rA * 33 + 8 + uA];
      const float gv = GATES_[rA * 33 + 16 + uA];
      const float ov = GATES_[rA * 33 + 24 + uA];
      const float cold = fresh ? 0.f : c1s;
      const float cn = sigf(fv) * cold + sigf(iv) * tanhfast(gv);
      c1s = cn;
      const float hv = sigf(ov) * tanhfast(cn);
      HOWN_[rA * 9 + uA] = hv;
      if (s < 7) {
        const unsigned hvb = f16u((_Float16)hv);
        const unsigned ob = (unsigned)__shfl_xor((int)hvb, 1) & 0xffffu;
        if ((uA & 1) == 0) {   // even lane packs {own, neighbor} hi16s + tag bits
          const unsigned hi = (ob & 0xFFFEu) | ((tagv >> 1) & 1u);
          mall_store_u32(h1x + gb * 32768 + sl * 4096 + rA * 128 + cw * 4 + (uA >> 1),
                         (hvb & 0xFFFEu) | 1u | (hi << 16));
        }
      }
      if (g == 126) {
        out[38912 + rA * 256 + cw * 8 + uA] = hv;   // h_n L1
        out[55296 + rA * 256 + cw * 8 + uA] = cn;   // c_n L1
      }
    }
    if (s == 7) __syncthreads();   // HOWN_ hazard only for the finishing slot

    // ---- s==7: head partials (tagged f32 PB) ----
    if (s == 7) {
      const int o = tid & 7;
      const float* wl = WLIN_ + o * 260 + cw * 8;
      const float* hb = HOWN_ + (tid >> 3) * 9;
      float p = 0.f;
#pragma unroll
      for (int u = 0; u < 8; ++u) p = fmaf(hb[u], wl[u], p);
      unsigned pu = (fbits(p) & ~3u) | tagv;
      mall_store_u32((unsigned*)pb + gb * 8192 + tid * 32 + cw, pu);
    }

    // ---- L: finisher -> colX + out; others -> packed h1X gather ----
    if (s == 7) {
      if (cw == 0) {
        const float* src = pb + gb * 8192 + tid * 32;
        f32x4 v0, v1, v2, v3, v4, v5, v6, v7;
        POLLPB(src, tagv)
        float pred = BLIN_[tid & 7]
            + v0.x + v0.y + v0.z + v0.w + v1.x + v1.y + v1.z + v1.w
            + v2.x + v2.y + v2.z + v2.w + v3.x + v3.y + v3.z + v3.w
            + v4.x + v4.y + v4.z + v4.w + v5.x + v5.y + v5.z + v5.w
            + v6.x + v6.y + v6.z + v6.w + v7.x + v7.y + v7.z + v7.w;
        const int r = tid >> 3, o = tid & 7;
        const float base = (t == 0) ? traj[r * 2048 + 7 * 16 + 8 + o]
                                    : BASE_[tid];
        const float v = base + pred;
        out[r * 960 + t * 8 + o] = v;               // exact f32 result
        const _Float16 hh = (_Float16)v;            // tagged mirror for feedback
        unsigned lo = f16u((_Float16)(v - (float)hh));
        lo = (lo & 0xFFFEu) | 1u;
        mall_store_u32(colx + t * 256 + tid, f16u(hh) | (lo << 16));
      }
      // finishing slot's next window is fresh: no h1 gather needed
    } else {
      const int r = tid >> 3, c32 = (tid & 7) << 5;
      const unsigned* src = h1x + gb * 32768 + sl * 4096 + r * 128 + (c32 >> 1);
      f32x4 v0, v1, v2, v3;
      POLL4H(src, tpat)
      unsigned* dst = (unsigned*)H1H_ + r * 132 + (c32 >> 1);
      WRM(v0, 0)  WRM(v1, 4)  WRM(v2, 8)  WRM(v3, 12)
    }
    __syncthreads();
  }
}

extern "C" void kernel_launch(void* const* d_in, const int* in_sizes, int n_in,
                              void* d_out, int out_size, void* d_ws, size_t ws_size,
                              hipStream_t stream) {
  (void)in_sizes; (void)n_in; (void)out_size; (void)ws_size;
  const float* traj = (const float*)d_in[0];
  const float* Wih0 = (const float*)d_in[1];
  const float* Whh0 = (const float*)d_in[2];
  const float* bih0 = (const float*)d_in[3];
  const float* bhh0 = (const float*)d_in[4];
  const float* Wih1 = (const float*)d_in[5];
  const float* Whh1 = (const float*)d_in[6];
  const float* bih1 = (const float*)d_in[7];
  const float* bhh1 = (const float*)d_in[8];
  const float* Wlin = (const float*)d_in[9];
  const float* blin = (const float*)d_in[10];
  float* out = (float*)d_out;
  char* wsb = (char*)d_ws;

  static bool attr_done = false;
  if (!attr_done) {
    (void)hipFuncSetAttribute((const void*)lstm_main,
                              hipFuncAttributeMaxDynamicSharedMemorySize,
                              SMEM_BYTES);
    attr_done = true;
  }

  hipMemsetAsync(d_ws, 0, CTRL_BYTES, stream);
  hipMemsetAsync(wsb + OFF_COLX, 0, PBCOLX_BYTES, stream);
  lstm_prep<<<1184, 256, 0, stream>>>(Wih0, Whh0, Wih1, Whh1, wsb);

  void* args[] = {(void*)&traj, (void*)&bih0, (void*)&bhh0, (void*)&bih1,
                  (void*)&bhh1, (void*)&Wlin, (void*)&blin, (void*)&out,
                  (void*)&wsb};
  hipLaunchCooperativeKernel((void*)lstm_main, dim3(NWG), dim3(TPB), args,
                             SMEM_BYTES, stream);
}

// Round 11
// 1057.335 us; speedup vs baseline: 1.6365x; 1.1312x over previous
//
#include <hip/hip_runtime.h>

// OR_LSTM Round 19: R18 + STORE-LINE PRIVATIZATION on h0X/h1X.
// B=32,T=128,D=16,H=256,WS=8,OUT=8. 127 iterations, 8-slot window pipeline,
// 256 wgs = 8 slots x 32 col-groups, TPB=256.
// R18 observation: halving h1X words didn't move WRITE_SIZE -- exchange
// stores are sub-line fragments; lines are the unit. Current layouts share
// each 128B MALL line across 4 wgs (h0X) / 8 wgs (h1X); concurrent sc1
// sub-line stores serialize on line ownership (consistent with R17's
// 32-wg/line blowup). R19 transposes both buffers to [cw][rA][uA]:
// every line written by exactly ONE wg in one contiguous 1KB/512B burst.
// Gathers become 4-chunk strided reads (same dwordx4 count, register
// ordering preserved -> UNPK/WRM untouched). Numerics bit-identical.
// PB/colX unchanged (single variable). Protocol identical to R18.

#define NWG 256
#define TPB 256

typedef float f32x4 __attribute__((ext_vector_type(4)));
typedef _Float16 f16x8 __attribute__((ext_vector_type(8)));
typedef unsigned u32x2 __attribute__((ext_vector_type(2)));

// ---- workspace byte layout ----
#define CTRL_BYTES 4096
#define OFF_W0H   36864      // f16 [1024 cols][296]   (init-only source)
#define OFF_W1AH  643072     // f16 [1024][256]        (init-only source)
#define OFF_W1AL  1167360
#define OFF_W1BH  1691648
#define OFF_W1BL  2215936
// overlays (live after init grid barriers; zeroed in-kernel between them):
#define OFF_H0X   OFF_W1AH   // u32 [2 par][8 sl][32 cw][32 r][8 u] {hi,lo+tag}
#define OFF_H1X   OFF_W1AL   // u32 [2 par][8 sl][32 cw][32 r][4 pair] hi-pack
// never-written-by-prep region (zeroed by memsetAsync):
#define OFF_COLX  2740224    // u32 [120 t][32 r][8 o]  {hi16, lo16|bit0}
#define OFF_PB    2863104    // f32 [2 par][256 (r*8+o)][32 cw]  bits1:0=tag
#define PBCOLX_BYTES 188416  // 122880 + 65536

// ---- ctrl u32 indices ----
#define IB1_U 32             // weights-read-done barrier
#define IB2_U 48             // zeroing-done barrier

// ---- dynamic LDS byte layout (<= 160KB) ----
#define L_W0H   0        // f16 [32][296]
#define L_W1AH  18944    // f16 [32][264]
#define L_W1AL  35840
#define L_W1BH  52736
#define L_W1BL  69632
#define L_ABH   86528    // f16 [32 rows][296]: x(0..15)|zero(16..31)|h0(32..287)
#define L_ABL   105472
#define L_H1H   124416   // f16 [32][264]
#define L_GATES 141312   // f32 [32][33]
#define L_WLIN  145536   // f32 [8][260]
#define L_HOWN  153856   // f32 [32][9]
#define L_BASE  155008   // f32 [32][8]
#define L_B0    156032
#define L_B1    156160
#define L_BLIN  156288
#define SMEM_BYTES 156320

__device__ __forceinline__ float sigf(float x) { return 1.0f / (1.0f + __expf(-x)); }
__device__ __forceinline__ float tanhfast(float x) {
  float e = __expf(2.0f * x);
  return 1.0f - 2.0f / (e + 1.0f);
}
__device__ __forceinline__ unsigned f16u(_Float16 h) {
  union { _Float16 h; unsigned short u; } c; c.h = h; return c.u;
}
__device__ __forceinline__ float uf16(unsigned u) {
  union { unsigned short s; _Float16 h; } c; c.s = (unsigned short)u; return (float)c.h;
}
__device__ __forceinline__ unsigned fbits(float x) {
  union { float f; unsigned u; } c; c.f = x; return c.u;
}
__device__ __forceinline__ void splitpack(float x0, float x1, unsigned& hw, unsigned& lw) {
  const _Float16 a = (_Float16)x0, b = (_Float16)x1;
  hw = f16u(a) | (f16u(b) << 16);
  lw = f16u((_Float16)(x0 - (float)a)) | (f16u((_Float16)(x1 - (float)b)) << 16);
}

__device__ __forceinline__ unsigned rload(const unsigned* p) {
  return __hip_atomic_load(p, __ATOMIC_RELAXED, __HIP_MEMORY_SCOPE_AGENT);
}
// MALL (device-coherent) ops: sc0 sc1 -- the proven primitives.
__device__ __forceinline__ void mall_store_u32(unsigned* p, unsigned v) {
  asm volatile("global_store_dword %0, %1, off sc0 sc1" :: "v"(p), "v"(v) : "memory");
}
__device__ __forceinline__ void mall_load2(const void* p, unsigned& x, unsigned& y) {
  u32x2 v;
  asm volatile("global_load_dwordx2 %0, %1, off sc0 sc1\n\ts_waitcnt vmcnt(0)"
               : "=v"(v) : "v"(p) : "memory");
  x = v.x; y = v.y;
}
// h0X gather: 4 chunks of 32B at 1KB stride (chunk k = cw (c32/8)+k).
__device__ __forceinline__ void mall_load8x4s(const void* p, f32x4& a0, f32x4& a1,
                                              f32x4& a2, f32x4& a3, f32x4& a4,
                                              f32x4& a5, f32x4& a6, f32x4& a7) {
  asm volatile(
      "global_load_dwordx4 %0, %8, off sc0 sc1\n\t"
      "global_load_dwordx4 %1, %8, off offset:16 sc0 sc1\n\t"
      "global_load_dwordx4 %2, %8, off offset:1024 sc0 sc1\n\t"
      "global_load_dwordx4 %3, %8, off offset:1040 sc0 sc1\n\t"
      "global_load_dwordx4 %4, %8, off offset:2048 sc0 sc1\n\t"
      "global_load_dwordx4 %5, %8, off offset:2064 sc0 sc1\n\t"
      "global_load_dwordx4 %6, %8, off offset:3072 sc0 sc1\n\t"
      "global_load_dwordx4 %7, %8, off offset:3088 sc0 sc1\n\t"
      "s_waitcnt vmcnt(0)"
      : "=&v"(a0), "=&v"(a1), "=&v"(a2), "=&v"(a3),
        "=&v"(a4), "=&v"(a5), "=&v"(a6), "=&v"(a7)
      : "v"(p) : "memory");
}
// h1X gather: 4 chunks of 16B at 512B stride.
__device__ __forceinline__ void mall_load4x4s(const void* p, f32x4& a, f32x4& b,
                                              f32x4& c, f32x4& d) {
  asm volatile(
      "global_load_dwordx4 %0, %4, off sc0 sc1\n\t"
      "global_load_dwordx4 %1, %4, off offset:512 sc0 sc1\n\t"
      "global_load_dwordx4 %2, %4, off offset:1024 sc0 sc1\n\t"
      "global_load_dwordx4 %3, %4, off offset:1536 sc0 sc1\n\t"
      "s_waitcnt vmcnt(0)"
      : "=&v"(a), "=&v"(b), "=&v"(c), "=&v"(d) : "v"(p) : "memory");
}
// PB funnel poll (unchanged layout): 128B contiguous.
__device__ __forceinline__ void mall_load8x4(const void* p, f32x4& a0, f32x4& a1,
                                             f32x4& a2, f32x4& a3, f32x4& a4,
                                             f32x4& a5, f32x4& a6, f32x4& a7) {
  asm volatile(
      "global_load_dwordx4 %0, %8, off sc0 sc1\n\t"
      "global_load_dwordx4 %1, %8, off offset:16 sc0 sc1\n\t"
      "global_load_dwordx4 %2, %8, off offset:32 sc0 sc1\n\t"
      "global_load_dwordx4 %3, %8, off offset:48 sc0 sc1\n\t"
      "global_load_dwordx4 %4, %8, off offset:64 sc0 sc1\n\t"
      "global_load_dwordx4 %5, %8, off offset:80 sc0 sc1\n\t"
      "global_load_dwordx4 %6, %8, off offset:96 sc0 sc1\n\t"
      "global_load_dwordx4 %7, %8, off offset:112 sc0 sc1\n\t"
      "s_waitcnt vmcnt(0)"
      : "=&v"(a0), "=&v"(a1), "=&v"(a2), "=&v"(a3),
        "=&v"(a4), "=&v"(a5), "=&v"(a6), "=&v"(a7)
      : "v"(p) : "memory");
}
__device__ __forceinline__ void vmdrain() {
  asm volatile("s_waitcnt vmcnt(0)" ::: "memory");
}
__device__ __forceinline__ f32x4 mfma16(f16x8 a, f16x8 b, f32x4 c) {
  return __builtin_amdgcn_mfma_f32_16x16x32_f16(a, b, c, 0, 0, 0);
}

// tag checks: h0X words carry tag in bits 17:16; PB f32 in bits 1:0;
// h1X packed words carry {bit0 = written, bit16 = generation}.
#define TG4(vv, TAG) ((((fbits(vv.x) >> 16) & 3u) == (TAG)) & (((fbits(vv.y) >> 16) & 3u) == (TAG)) & \
                      (((fbits(vv.z) >> 16) & 3u) == (TAG)) & (((fbits(vv.w) >> 16) & 3u) == (TAG)))
#define TP4(vv, TAG) (((fbits(vv.x) & 3u) == (TAG)) & ((fbits(vv.y) & 3u) == (TAG)) & \
                      ((fbits(vv.z) & 3u) == (TAG)) & ((fbits(vv.w) & 3u) == (TAG)))
#define TH4(vv, TPAT) (((fbits(vv.x) & 0x10001u) == (TPAT)) & ((fbits(vv.y) & 0x10001u) == (TPAT)) & \
                       ((fbits(vv.z) & 0x10001u) == (TPAT)) & ((fbits(vv.w) & 0x10001u) == (TPAT)))
#define UNPK(vv, i2) {                                              \
    const unsigned w0 = fbits(vv.x), w1 = fbits(vv.y);              \
    const unsigned w2 = fbits(vv.z), w3 = fbits(vv.w);              \
    ah32[(i2)]     = (w0 & 0xffffu) | (w1 << 16);                   \
    ah32[(i2) + 1] = (w2 & 0xffffu) | (w3 << 16);                   \
    al32[(i2)]     = (w0 >> 16) | (w1 & 0xffff0000u);               \
    al32[(i2) + 1] = (w2 >> 16) | (w3 & 0xffff0000u); }
#define WRM(vv, i) {                                                \
    dst[(i)]     = fbits(vv.x) & 0xFFFEFFFEu;                       \
    dst[(i) + 1] = fbits(vv.y) & 0xFFFEFFFEu;                       \
    dst[(i) + 2] = fbits(vv.z) & 0xFFFEFFFEu;                       \
    dst[(i) + 3] = fbits(vv.w) & 0xFFFEFFFEu; }
#define POLL8S(srcp, TAG)                                            \
  { while (true) {                                                   \
      mall_load8x4s(srcp, v0, v1, v2, v3, v4, v5, v6, v7);           \
      const unsigned ok = TG4(v0,TAG) & TG4(v1,TAG) & TG4(v2,TAG) &  \
                          TG4(v3,TAG) & TG4(v4,TAG) & TG4(v5,TAG) &  \
                          TG4(v6,TAG) & TG4(v7,TAG);                 \
      if (ok) break;                                                 \
    } }
#define POLLPB(srcp, TAG)                                            \
  { while (true) {                                                   \
      mall_load8x4(srcp, v0, v1, v2, v3, v4, v5, v6, v7);            \
      const unsigned ok = TP4(v0,TAG) & TP4(v1,TAG) & TP4(v2,TAG) &  \
                          TP4(v3,TAG) & TP4(v4,TAG) & TP4(v5,TAG) &  \
                          TP4(v6,TAG) & TP4(v7,TAG);                 \
      if (ok) break;                                                 \
    } }
#define POLL4HS(srcp, TPAT)                                          \
  { while (true) {                                                   \
      mall_load4x4s(srcp, v0, v1, v2, v3);                           \
      const unsigned ok = TH4(v0,TPAT) & TH4(v1,TPAT) &              \
                          TH4(v2,TPAT) & TH4(v3,TPAT);               \
      if (ok) break;                                                 \
    } }

// ---- prep (unchanged): pack weights into frag-ready f16 planes ----
__global__ __launch_bounds__(256) void lstm_prep(
    const float* __restrict__ Wih0, const float* __restrict__ Whh0,
    const float* __restrict__ Wih1, const float* __restrict__ Whh1,
    char* __restrict__ wsb) {
  const int i = blockIdx.x * 256 + threadIdx.x;
  _Float16* W0H = (_Float16*)(wsb + OFF_W0H);
  _Float16* W1AH = (_Float16*)(wsb + OFF_W1AH);
  _Float16* W1AL = (_Float16*)(wsb + OFF_W1AL);
  _Float16* W1BH = (_Float16*)(wsb + OFF_W1BH);
  _Float16* W1BL = (_Float16*)(wsb + OFF_W1BL);
  if (i < 1024 * 296) {           // W0 hi-only
    const int cg = i / 296, k = i - cg * 296;
    const int cw = cg >> 5, c = cg & 31;
    const int J = (c >> 3) * 256 + cw * 8 + (c & 7);
    float w = 0.f;
    if (k < 16) w = Wih0[J * 16 + k];
    else if (k >= 32 && k < 288) w = Whh0[J * 256 + (k - 32)];
    W0H[i] = (_Float16)w;
  }
  if (i < 1024 * 256) {           // W1A/W1B hi+lo
    const int cg = i >> 8, k = i & 255;
    const int cw = cg >> 5, c = cg & 31;
    const int J = (c >> 3) * 256 + cw * 8 + (c & 7);
    const float wa = Wih1[J * 256 + k];
    _Float16 h = (_Float16)wa;
    W1AH[i] = h; W1AL[i] = (_Float16)(wa - (float)h);
    const float wb = Whh1[J * 256 + k];
    h = (_Float16)wb;
    W1BH[i] = h; W1BL[i] = (_Float16)(wb - (float)h);
  }
}

__global__ __launch_bounds__(TPB, 1) void lstm_main(
    const float* __restrict__ traj,
    const float* __restrict__ bih0, const float* __restrict__ bhh0,
    const float* __restrict__ bih1, const float* __restrict__ bhh1,
    const float* __restrict__ Wlin, const float* __restrict__ blin,
    float* __restrict__ out, char* __restrict__ wsb) {
  extern __shared__ char smem[];
  _Float16* const W0H_  = (_Float16*)(smem + L_W0H);
  _Float16* const W1AH_ = (_Float16*)(smem + L_W1AH);
  _Float16* const W1AL_ = (_Float16*)(smem + L_W1AL);
  _Float16* const W1BH_ = (_Float16*)(smem + L_W1BH);
  _Float16* const W1BL_ = (_Float16*)(smem + L_W1BL);
  _Float16* const ABH_  = (_Float16*)(smem + L_ABH);
  _Float16* const ABL_  = (_Float16*)(smem + L_ABL);
  _Float16* const H1H_  = (_Float16*)(smem + L_H1H);
  float* const GATES_ = (float*)(smem + L_GATES);
  float* const WLIN_  = (float*)(smem + L_WLIN);
  float* const HOWN_  = (float*)(smem + L_HOWN);
  float* const BASE_  = (float*)(smem + L_BASE);
  float* const B0_    = (float*)(smem + L_B0);
  float* const B1_    = (float*)(smem + L_B1);
  float* const BLIN_  = (float*)(smem + L_BLIN);

  const int tid = threadIdx.x;
  const int wg = blockIdx.x;
  const int sl = wg & 7;           // pipeline slot
  const int cw = wg >> 3;          // col-group: units [cw*8, cw*8+8)
  unsigned* ctrl = (unsigned*)wsb;
  unsigned* const h0x = (unsigned*)(wsb + OFF_H0X);
  unsigned* const h1x = (unsigned*)(wsb + OFF_H1X);
  unsigned* const colx = (unsigned*)(wsb + OFF_COLX);
  float* const pb = (float*)(wsb + OFF_PB);

  // ---- one-time LDS init from packed ws ----
  {
    const unsigned* s0 = (const unsigned*)(wsb + OFF_W0H) + cw * 4736;
    unsigned* d0 = (unsigned*)W0H_;
    for (int i = tid; i < 4736; i += TPB) d0[i] = s0[i];
    const unsigned* s1 = (const unsigned*)(wsb + OFF_W1AH) + cw * 4096;
    const unsigned* s2 = (const unsigned*)(wsb + OFF_W1AL) + cw * 4096;
    const unsigned* s3 = (const unsigned*)(wsb + OFF_W1BH) + cw * 4096;
    const unsigned* s4 = (const unsigned*)(wsb + OFF_W1BL) + cw * 4096;
    unsigned* d1 = (unsigned*)W1AH_; unsigned* d2 = (unsigned*)W1AL_;
    unsigned* d3 = (unsigned*)W1BH_; unsigned* d4 = (unsigned*)W1BL_;
    for (int i = tid; i < 4096; i += TPB) {
      const int c = i >> 7, d = i & 127;  // restride 128 -> 132 dwords
      d1[c * 132 + d] = s1[i];
      d2[c * 132 + d] = s2[i];
      d3[c * 132 + d] = s3[i];
      d4[c * 132 + d] = s4[i];
    }
    for (int i = tid; i < 2048; i += TPB)
      WLIN_[(i >> 8) * 260 + (i & 255)] = Wlin[i];
    if (tid < 32) {
      const int J = (tid >> 3) * 256 + cw * 8 + (tid & 7);
      B0_[tid] = bih0[J] + bhh0[J];
      B1_[tid] = bih1[J] + bhh1[J];
    }
    if (tid < 8) BLIN_[tid] = blin[tid];
    {  // permanent zero pad k=16..31 of AB
      const int r = tid >> 3, q = tid & 7;
      ((unsigned*)ABH_)[r * 148 + 8 + q] = 0u;
      ((unsigned*)ABL_)[r * 148 + 8 + q] = 0u;
    }
  }
  // grid barrier 1: everyone done READING overlay weight regions
  __syncthreads();
  if (tid == 0) {
    __hip_atomic_fetch_add(&ctrl[IB1_U], 1u, __ATOMIC_RELAXED,
                           __HIP_MEMORY_SCOPE_AGENT);
    while (rload(&ctrl[IB1_U]) < NWG) __builtin_amdgcn_s_sleep(1);
  }
  __syncthreads();
  // zero OWN (sl,cw) exchange ranges (both parities; producer-contiguous)
  {
    const int b = sl * 8192 + cw * 256 + tid;
    mall_store_u32(h0x + b, 0u);
    mall_store_u32(h0x + 65536 + b, 0u);
    if (tid < 128) {   // h1X packed: 128 contiguous words per parity per wg
      const int w = sl * 4096 + cw * 128 + tid;
      mall_store_u32(h1x + w, 0u);
      mall_store_u32(h1x + 32768 + w, 0u);
    }
    vmdrain();
  }
  // grid barrier 2: zeroing visible before any exchange
  __syncthreads();
  if (tid == 0) {
    __hip_atomic_fetch_add(&ctrl[IB2_U], 1u, __ATOMIC_RELAXED,
                           __HIP_MEMORY_SCOPE_AGENT);
    while (rload(&ctrl[IB2_U]) < NWG) __builtin_amdgcn_s_sleep(1);
  }
  __syncthreads();

  // per-thread constants
  const int l = tid & 63, wv = tid >> 6;
  const int frow = ((wv >> 1) << 4) + (l & 15);
  const int fcol = ((wv & 1) << 4) + (l & 15);
  const int kg = (l >> 4) << 3;
  const int gr = ((wv >> 1) << 4) + ((l >> 4) << 2);
  const int rA = tid >> 3, uA = tid & 7;
  // strided gather bases (word offsets within a slot's region):
  //   h0X: chunk cw0 = (tid&7)*4, base = cw0*256 + r*8
  //   h1X: base = cw0*128 + r*4
  const int g0base = ((tid & 7) << 2) * 256 + (tid >> 3) * 8;
  const int g1base = ((tid & 7) << 2) * 128 + (tid >> 3) * 4;

  float c0s = 0.f, c1s = 0.f;

  for (int g = 0; g < 127; ++g) {
    const int s = (g - sl) & 7;
    const int t = g - s;
    if (t < 0 || t > 119) continue;
    const bool fresh = (s == 0);
    const int gb = g & 1;                            // buffer parity
    const unsigned tagv = 1u | (((unsigned)(g >> 1) & 1u) << 1);  // {bit1,bit0}
    const unsigned tpat = 1u | (((tagv >> 1) & 1u) << 16);        // h1X pattern

    // ---- A: L0 h0-part (pre-feedback; AB h0 gathered last iteration) ----
    f32x4 acc0;
    { const float b = B0_[fcol]; acc0 = (f32x4){b, b, b, b}; }
    if (!fresh) {
      for (int ks = 0; ks < 8; ++ks) {
        const f16x8 ah = *(const f16x8*)(ABH_ + frow * 296 + 32 + ks * 32 + kg);
        const f16x8 al = *(const f16x8*)(ABL_ + frow * 296 + 32 + ks * 32 + kg);
        const f16x8 wh = *(const f16x8*)(W0H_ + fcol * 296 + 32 + ks * 32 + kg);
        acc0 = mfma16(ah, wh, acc0);
        acc0 = mfma16(al, wh, acc0);
      }
    }

    // ---- D: stage x -> AB[0..15]; feedback dims poll tagged colX ----
    {
      const int r = tid >> 3, dp = (tid & 7) << 1;
      unsigned hw, lw;
      if (t <= 7 && s < 8 - t) {
        const float* tp = traj + r * 2048 + (t + s) * 16 + dp;
        splitpack(tp[0], tp[1], hw, lw);
      } else if (dp < 8) {
        const int ti = (t <= 7) ? (2 * t + s - 1) : (t + s);
        const float* tp = traj + r * 2048 + ti * 16 + dp;
        splitpack(tp[0], tp[1], hw, lw);
      } else {
        const unsigned* cp = colx + (g - 8) * 256 + r * 8 + (dp - 8);
        unsigned w0, w1;
        do { mall_load2(cp, w0, w1); } while (!(w0 & 0x10000u) || !(w1 & 0x10000u));
        hw = (w0 & 0xffffu) | ((w1 & 0xffffu) << 16);
        lw = (w0 >> 16) | (w1 & 0xffff0000u);
        if (s == 7) {  // cache finisher base out[:,t-1]
          BASE_[r * 8 + dp - 8] = uf16(w0 & 0xffffu) + uf16(w0 >> 16);
          BASE_[r * 8 + dp - 7] = uf16(w1 & 0xffffu) + uf16(w1 >> 16);
        }
      }
      ((unsigned*)ABH_)[r * 148 + (dp >> 1)] = hw;
      ((unsigned*)ABL_)[r * 148 + (dp >> 1)] = lw;
    }
    __syncthreads();

    // ---- E: L0 x k-step, gates out ----
    {
      const f16x8 ah = *(const f16x8*)(ABH_ + frow * 296 + kg);
      const f16x8 al = *(const f16x8*)(ABL_ + frow * 296 + kg);
      const f16x8 wh = *(const f16x8*)(W0H_ + fcol * 296 + kg);
      acc0 = mfma16(ah, wh, acc0);
      acc0 = mfma16(al, wh, acc0);
#pragma unroll
      for (int q = 0; q < 4; ++q) GATES_[(gr + q) * 33 + fcol] = acc0[q];
    }
    __syncthreads();

    // ---- F: L0 act + tagged h0X publish (producer-contiguous: word=tid) ----
    {
      const float iv = GATES_[rA * 33 + uA];
      const float fv = GATES_[rA * 33 + 8 + uA];
      const float gv = GATES_[rA * 33 + 16 + uA];
      const float ov = GATES_[rA * 33 + 24 + uA];
      const float cold = fresh ? 0.f : c0s;
      const float cn = sigf(fv) * cold + sigf(iv) * tanhfast(gv);
      c0s = cn;
      const float hv = sigf(ov) * tanhfast(cn);
      const _Float16 hh = (_Float16)hv;
      unsigned lo = f16u((_Float16)(hv - (float)hh));
      lo = (lo & 0xFFFCu) | tagv;
      mall_store_u32(h0x + gb * 65536 + sl * 8192 + cw * 256 + rA * 8 + uA,
                     f16u(hh) | (lo << 16));
      if (g == 126) {
        out[30720 + rA * 256 + cw * 8 + uA] = hv;   // h_n L0
        out[47104 + rA * 256 + cw * 8 + uA] = cn;   // c_n L0
      }
    }

    // ---- B': W1B*h1 (register-only; fills the h0X store->poll window) ----
    f32x4 acc1;
    { const float b = B1_[fcol]; acc1 = (f32x4){b, b, b, b}; }
    if (!fresh) {
      for (int ks = 0; ks < 8; ++ks) {
        const f16x8 hh = *(const f16x8*)(H1H_ + frow * 264 + ks * 32 + kg);
        const f16x8 wh = *(const f16x8*)(W1BH_ + fcol * 264 + ks * 32 + kg);
        const f16x8 wl = *(const f16x8*)(W1BL_ + fcol * 264 + ks * 32 + kg);
        acc1 = mfma16(hh, wh, acc1);
        acc1 = mfma16(hh, wl, acc1);
      }
    }

    // ---- H: poll-gather tagged h0X (4-chunk strided) -> AB[32..287] ----
    {
      const int r = tid >> 3, c32 = (tid & 7) << 5;
      const unsigned* src = h0x + gb * 65536 + sl * 8192 + g0base;
      f32x4 v0, v1, v2, v3, v4, v5, v6, v7;
      POLL8S(src, tagv)
      unsigned* ah32 = (unsigned*)ABH_ + r * 148 + 16 + (c32 >> 1);
      unsigned* al32 = (unsigned*)ABL_ + r * 148 + 16 + (c32 >> 1);
      UNPK(v0, 0)  UNPK(v1, 2)  UNPK(v2, 4)  UNPK(v3, 6)
      UNPK(v4, 8)  UNPK(v5, 10) UNPK(v6, 12) UNPK(v7, 14)
    }
    __syncthreads();

    // ---- I: L1 W1A part (3 products), gates out ----
    {
      for (int ks = 0; ks < 8; ++ks) {
        const f16x8 ah = *(const f16x8*)(ABH_ + frow * 296 + 32 + ks * 32 + kg);
        const f16x8 al = *(const f16x8*)(ABL_ + frow * 296 + 32 + ks * 32 + kg);
        const f16x8 wh = *(const f16x8*)(W1AH_ + fcol * 264 + ks * 32 + kg);
        const f16x8 wl = *(const f16x8*)(W1AL_ + fcol * 264 + ks * 32 + kg);
        acc1 = mfma16(ah, wh, acc1);
        acc1 = mfma16(al, wh, acc1);
        acc1 = mfma16(ah, wl, acc1);
      }
#pragma unroll
      for (int q = 0; q < 4; ++q) GATES_[(gr + q) * 33 + fcol] = acc1[q];
    }
    __syncthreads();

    // ---- J: L1 act; HOWN; packed hi-only h1X publish (s<7) ----
    {
      const float iv = GATES_[rA * 33 + uA];
      const float fv = GATES_[rA * 33 + 8 + uA];
      const float gv = GATES_[rA * 33 + 16 + uA];
      const float ov = GATES_[rA * 33 + 24 + uA];
      const float cold = fresh ? 0.f : c1s;
      const float cn = sigf(fv) * cold + sigf(iv) * tanhfast(gv);
      c1s = cn;
      const float hv = sigf(ov) * tanhfast(cn);
      HOWN_[rA * 9 + uA] = hv;
      if (s < 7) {
        const unsigned hvb = f16u((_Float16)hv);
        const unsigned ob = (unsigned)__shfl_xor((int)hvb, 1) & 0xffffu;
        if ((uA & 1) == 0) {   // even lane packs {own, neighbor} hi16s + tag bits
          const unsigned hi = (ob & 0xFFFEu) | ((tagv >> 1) & 1u);
          mall_store_u32(h1x + gb * 32768 + sl * 4096 + cw * 128 + rA * 4 + (uA >> 1),
                         (hvb & 0xFFFEu) | 1u | (hi << 16));
        }
      }
      if (g == 126) {
        out[38912 + rA * 256 + cw * 8 + uA] = hv;   // h_n L1
        out[55296 + rA * 256 + cw * 8 + uA] = cn;   // c_n L1
      }
    }
    if (s == 7) __syncthreads();   // HOWN_ hazard only for the finishing slot

    // ---- s==7: head partials (tagged f32 PB) ----
    if (s == 7) {
      const int o = tid & 7;
      const float* wl = WLIN_ + o * 260 + cw * 8;
      const float* hb = HOWN_ + (tid >> 3) * 9;
      float p = 0.f;
#pragma unroll
      for (int u = 0; u < 8; ++u) p = fmaf(hb[u], wl[u], p);
      unsigned pu = (fbits(p) & ~3u) | tagv;
      mall_store_u32((unsigned*)pb + gb * 8192 + tid * 32 + cw, pu);
    }

    // ---- L: finisher -> colX + out; others -> packed h1X gather ----
    if (s == 7) {
      if (cw == 0) {
        const float* src = pb + gb * 8192 + tid * 32;
        f32x4 v0, v1, v2, v3, v4, v5, v6, v7;
        POLLPB(src, tagv)
        float pred = BLIN_[tid & 7]
            + v0.x + v0.y + v0.z + v0.w + v1.x + v1.y + v1.z + v1.w
            + v2.x + v2.y + v2.z + v2.w + v3.x + v3.y + v3.z + v3.w
            + v4.x + v4.y + v4.z + v4.w + v5.x + v5.y + v5.z + v5.w
            + v6.x + v6.y + v6.z + v6.w + v7.x + v7.y + v7.z + v7.w;
        const int r = tid >> 3, o = tid & 7;
        const float base = (t == 0) ? traj[r * 2048 + 7 * 16 + 8 + o]
                                    : BASE_[tid];
        const float v = base + pred;
        out[r * 960 + t * 8 + o] = v;               // exact f32 result
        const _Float16 hh = (_Float16)v;            // tagged mirror for feedback
        unsigned lo = f16u((_Float16)(v - (float)hh));
        lo = (lo & 0xFFFEu) | 1u;
        mall_store_u32(colx + t * 256 + tid, f16u(hh) | (lo << 16));
      }
      // finishing slot's next window is fresh: no h1 gather needed
    } else {
      const int r = tid >> 3, c32 = (tid & 7) << 5;
      const unsigned* src = h1x + gb * 32768 + sl * 4096 + g1base;
      f32x4 v0, v1, v2, v3;
      POLL4HS(src, tpat)
      unsigned* dst = (unsigned*)H1H_ + r * 132 + (c32 >> 1);
      WRM(v0, 0)  WRM(v1, 4)  WRM(v2, 8)  WRM(v3, 12)
    }
    __syncthreads();
  }
}

extern "C" void kernel_launch(void* const* d_in, const int* in_sizes, int n_in,
                              void* d_out, int out_size, void* d_ws, size_t ws_size,
                              hipStream_t stream) {
  (void)in_sizes; (void)n_in; (void)out_size; (void)ws_size;
  const float* traj = (const float*)d_in[0];
  const float* Wih0 = (const float*)d_in[1];
  const float* Whh0 = (const float*)d_in[2];
  const float* bih0 = (const float*)d_in[3];
  const float* bhh0 = (const float*)d_in[4];
  const float* Wih1 = (const float*)d_in[5];
  const float* Whh1 = (const float*)d_in[6];
  const float* bih1 = (const float*)d_in[7];
  const float* bhh1 = (const float*)d_in[8];
  const float* Wlin = (const float*)d_in[9];
  const float* blin = (const float*)d_in[10];
  float* out = (float*)d_out;
  char* wsb = (char*)d_ws;

  static bool attr_done = false;
  if (!attr_done) {
    (void)hipFuncSetAttribute((const void*)lstm_main,
                              hipFuncAttributeMaxDynamicSharedMemorySize,
                              SMEM_BYTES);
    attr_done = true;
  }

  hipMemsetAsync(d_ws, 0, CTRL_BYTES, stream);
  hipMemsetAsync(wsb + OFF_COLX, 0, PBCOLX_BYTES, stream);
  lstm_prep<<<1184, 256, 0, stream>>>(Wih0, Whh0, Wih1, Whh1, wsb);

  void* args[] = {(void*)&traj, (void*)&bih0, (void*)&bhh0, (void*)&bih1,
                  (void*)&bhh1, (void*)&Wlin, (void*)&blin, (void*)&out,
                  (void*)&wsb};
  hipLaunchCooperativeKernel((void*)lstm_main, dim3(NWG), dim3(TPB), args,
                             SMEM_BYTES, stream);
}